// Round 6
// baseline (139.017 us; speedup 1.0000x reference)
//
#include <hip/hip_runtime.h>
#include <stdint.h>

#define NN 50000
#define NE 800000
#define KDIM 256
#define DDIM 64
#define ALPHA 0.2f
#define EPSV 9e-15f

#define NBIN 512
#define BSPAN 98           // nodes per bin; 512*98 = 50176 >= 50000
#define SPAN2 49           // nodes per half-bin (k_agg block granularity)
#define BCAP 2048          // edge capacity per bin (mean 1562, +12 sigma)
#define HCAP 1024          // edge capacity per half-bin
#define PBLK 512           // partition-role blocks
#define EPB 1563           // ceil(NE / PBLK); last block handles 1307
#define GEMM_BLOCKS 784    // 3136 waves >= 3125 tiles
#define FGRID (PBLK + GEMM_BLOCKS)

// d_ws layout in 4-byte words:
#define O_S    0           // 50000 f32
#define O_T    50000       // 50000 f32
#define O_HB   100000      // 3.2M ushort = 1.6M words (bf16 H)
#define O_WB   1700000     // 2048 uint4 = 8192 words (prepacked bf16 W)
#define O_BIN  1708192     // 512 uint (bin fill counters, zeroed by k_prep)
#define O_EBUF 1708704     // NBIN*BCAP = 1,048,576 words (binned packed edges)
// total 2,757,280 words = 11.03 MB

typedef __bf16 bf16x8 __attribute__((ext_vector_type(8)));
typedef float f32x4 __attribute__((ext_vector_type(4)));

__device__ __forceinline__ ushort f2bf(float f) {
    uint32_t u = __float_as_uint(f);
    return (ushort)((u + 0x7fffu + ((u >> 16) & 1u)) >> 16);  // RNE
}
__device__ __forceinline__ float bf2f(ushort u) {
    return __uint_as_float(((uint32_t)u) << 16);
}
// exact floor(src/98) for src < 89240:  85599*98 - 2^23 = 94
__device__ __forceinline__ uint binof(uint src) {
    return (src * 85599u) >> 23;
}

// ---- K0: prep — pack W to bf16 LDS layout; zero bin counters ----
__global__ __launch_bounds__(256) void k_prep(const float* __restrict__ W,
                                              uint* __restrict__ BINCNT,
                                              uint4* __restrict__ WB) {
    const int g = blockIdx.x * 256 + threadIdx.x;  // 8 blocks -> 2048 threads
    if (g < NBIN) BINCNT[g] = 0u;
    if (g < 2048) {
        int ts = g >> 6;
        int ln = g & 63;
        int s = ts >> 2, t = ts & 3;
        int q = ln >> 4, c = ln & 15;
        union { ushort us[8]; uint4 v; } pk;
#pragma unroll
        for (int j = 0; j < 8; ++j) {
            int k = s * 32 + q * 8 + j;
            pk.us[j] = f2bf(W[k * DDIM + t * 16 + c]);
        }
        WB[g] = pk.v;
    }
}

// ---- K1: fused edge-partition (blocks 0..511) + gemm (blocks 512..1295) ----
__global__ __launch_bounds__(256) void k_fused(const float* __restrict__ X,
                                               const uint4* __restrict__ WB,
                                               const float* __restrict__ attn,
                                               const int* __restrict__ edge,
                                               ushort* __restrict__ HB,
                                               float* __restrict__ S,
                                               float* __restrict__ T,
                                               uint* __restrict__ BINCNT,
                                               uint* __restrict__ EBUF) {
    __shared__ uint4 bsm[2048];  // 32 KB, role-dependent use

    if (blockIdx.x < PBLK) {
        // ---------------- partition role: LDS counting sort by bin ----------
        // layout (words): cnt/cursor 0..511 | binStart 512..1023 |
        //   gbase 1024..1535 | stag 1536..3098 | sorted 3099..4661  (18.6 KB)
        uint* sm = (uint*)bsm;
        const int CNT0 = 0, BST = 512, GBS = 1024, STG = 1536, SRT = 3099;
        const int tid = threadIdx.x;
        const int p0 = blockIdx.x * EPB;
        const int nv = (NE - p0) < EPB ? (NE - p0) : EPB;  // valid edges here
        for (int b = tid; b < NBIN; b += 256) sm[CNT0 + b] = 0u;
        __syncthreads();
        for (int k = tid; k < nv; k += 256) {
            uint s = (uint)edge[p0 + k];
            uint d = (uint)edge[NE + p0 + k];
            sm[STG + k] = s | (d << 16);
            atomicAdd(&sm[CNT0 + binof(s)], 1u);
        }
        __syncthreads();
        // exclusive scan of cnt -> binStart (wave 0)
        if (tid < 64) {
            uint carry = 0;
            for (int c = 0; c < 8; ++c) {
                uint v = sm[CNT0 + c * 64 + tid];
                uint incl = v;
#pragma unroll
                for (int m = 1; m < 64; m <<= 1) {
                    uint t = __shfl_up(incl, m, 64);
                    if (tid >= m) incl += t;
                }
                sm[BST + c * 64 + tid] = incl - v + carry;
                carry += __shfl(incl, 63, 64);
            }
        }
        __syncthreads();
        // reserve global space per bin; repurpose cnt[] as LDS scatter cursor
        for (int b = tid; b < NBIN; b += 256) {
            uint c = sm[CNT0 + b];
            sm[GBS + b] = c ? atomicAdd(&BINCNT[b], c) : 0u;
            sm[CNT0 + b] = sm[BST + b];
        }
        __syncthreads();
        // LDS scatter: bin-sorted order
        for (int k = tid; k < nv; k += 256) {
            uint pk = sm[STG + k];
            uint bin = binof(pk & 0xffffu);
            uint slot = atomicAdd(&sm[CNT0 + bin], 1u);
            sm[SRT + slot] = pk;
        }
        __syncthreads();
        // copy-out: bin is directly computable from payload (no search)
        for (int k = tid; k < nv; k += 256) {
            uint pk = sm[SRT + k];
            uint bin = binof(pk & 0xffffu);
            uint local = (uint)k - sm[BST + bin] + sm[GBS + bin];
            if (local < BCAP) EBUF[bin * BCAP + local] = pk;
        }
        return;
    }

    // ---------------- gemm role ----------------
    uint4 wreg[8];
#pragma unroll
    for (int j = 0; j < 8; ++j) wreg[j] = WB[j * 256 + threadIdx.x];
#pragma unroll
    for (int j = 0; j < 8; ++j) bsm[j * 256 + threadIdx.x] = wreg[j];
    __syncthreads();

    const int lane = threadIdx.x & 63;
    const int wave = (blockIdx.x - PBLK) * 4 + (threadIdx.x >> 6);
    const int nwaves = GEMM_BLOCKS * 4;  // 3136
    const int quad = lane >> 4;
    const int nn = lane & 15;

    float asrc[4], adst[4];
#pragma unroll
    for (int t = 0; t < 4; ++t) {
        asrc[t] = attn[t * 16 + nn];
        adst[t] = attn[DDIM + t * 16 + nn];
    }

    const int MT = NN / 16;  // 3125
    for (int mt = wave; mt < MT; mt += nwaves) {
        const int row0 = mt * 16;
        const float* xr = X + (size_t)(row0 + nn) * KDIM + quad * 8;
        bf16x8 afrag[8];
#pragma unroll
        for (int s = 0; s < 8; ++s) {
            float4 lo = *reinterpret_cast<const float4*>(xr + s * 32);
            float4 hi = *reinterpret_cast<const float4*>(xr + s * 32 + 4);
            union { uint u[4]; bf16x8 v; } aa;
            asm("v_cvt_pk_bf16_f32 %0, %1, %2"
                : "=v"(aa.u[0]) : "v"(lo.x), "v"(lo.y));
            asm("v_cvt_pk_bf16_f32 %0, %1, %2"
                : "=v"(aa.u[1]) : "v"(lo.z), "v"(lo.w));
            asm("v_cvt_pk_bf16_f32 %0, %1, %2"
                : "=v"(aa.u[2]) : "v"(hi.x), "v"(hi.y));
            asm("v_cvt_pk_bf16_f32 %0, %1, %2"
                : "=v"(aa.u[3]) : "v"(hi.z), "v"(hi.w));
            afrag[s] = aa.v;
        }

        f32x4 acc[4];
#pragma unroll
        for (int t = 0; t < 4; ++t) acc[t] = {0.f, 0.f, 0.f, 0.f};
#pragma unroll
        for (int s = 0; s < 8; ++s)
#pragma unroll
            for (int t = 0; t < 4; ++t) {
                bf16x8 bf = *reinterpret_cast<const bf16x8*>(
                    &bsm[(s * 4 + t) * 64 + lane]);
                acc[t] = __builtin_amdgcn_mfma_f32_16x16x32_bf16(
                    afrag[s], bf, acc[t], 0, 0, 0);
            }

#pragma unroll
        for (int t = 0; t < 4; ++t)
#pragma unroll
            for (int r = 0; r < 4; ++r)
                HB[(size_t)(row0 + quad * 4 + r) * DDIM + t * 16 + nn] =
                    f2bf(acc[t][r]);

        float sp[4], tp[4];
#pragma unroll
        for (int r = 0; r < 4; ++r) { sp[r] = 0.f; tp[r] = 0.f; }
#pragma unroll
        for (int t = 0; t < 4; ++t)
#pragma unroll
            for (int r = 0; r < 4; ++r) {
                sp[r] = fmaf(acc[t][r], asrc[t], sp[r]);
                tp[r] = fmaf(acc[t][r], adst[t], tp[r]);
            }
#pragma unroll
        for (int m = 1; m < 16; m <<= 1)
#pragma unroll
            for (int r = 0; r < 4; ++r) {
                sp[r] += __shfl_xor(sp[r], m, 64);
                tp[r] += __shfl_xor(tp[r], m, 64);
            }
        if (nn == 0) {
#pragma unroll
            for (int r = 0; r < 4; ++r) {
                S[row0 + quad * 4 + r] = sp[r];
                T[row0 + quad * 4 + r] = tp[r];
            }
        }
    }
}

// ---- K2: half-bin aggregation with in-LDS CSR + register accumulation ----
// (unchanged from round 5 — measured fast)
__global__ __launch_bounds__(512) void k_agg(const uint* __restrict__ EBUF,
                                             const uint* __restrict__ BINCNT,
                                             const float* __restrict__ S,
                                             const float* __restrict__ T,
                                             const ushort* __restrict__ HB,
                                             float* __restrict__ out) {
    __shared__ uint2 sDE[HCAP];       // (dst, e-bits) row-sorted, 8 KB
    __shared__ uint  cntL[SPAN2];
    __shared__ uint  off[SPAN2 + 1];
    __shared__ uint  cur[SPAN2];
    __shared__ float Sseg[SPAN2];

    const int b = blockIdx.x >> 1;
    const int half = blockIdx.x & 1;
    const int nb0 = b * BSPAN + half * SPAN2;
    const int tid = threadIdx.x;

    if (tid < SPAN2) {
        cntL[tid] = 0u;
        int node = nb0 + tid;
        Sseg[tid] = (node < NN) ? S[node] : 0.f;
    }
    __syncthreads();

    int cnt = (int)BINCNT[b];
    cnt = cnt < BCAP ? cnt : BCAP;
    const uint* eb = EBUF + b * BCAP;

    // (1) histogram of our half's rows
    for (int k = tid; k < cnt; k += 512) {
        int row = (int)(eb[k] & 0xffffu) - nb0;
        if ((unsigned)row < SPAN2) atomicAdd(&cntL[row], 1u);
    }
    __syncthreads();

    // (2) exclusive scan, 49 values, wave 0
    if (tid < 64) {
        uint v = (tid < SPAN2) ? cntL[tid] : 0u;
        uint incl = v;
#pragma unroll
        for (int m = 1; m < 64; m <<= 1) {
            uint t = __shfl_up(incl, m, 64);
            if (tid >= m) incl += t;
        }
        if (tid < SPAN2) { off[tid] = incl - v; cur[tid] = incl - v; }
        if (tid == SPAN2 - 1) off[SPAN2] = incl;
    }
    __syncthreads();

    // (3) scatter + logit computation (edges are L2-hot from pass 1)
    for (int k = tid; k < cnt; k += 512) {
        uint pk = eb[k];
        int row = (int)(pk & 0xffffu) - nb0;
        if ((unsigned)row < SPAN2) {
            float v = Sseg[row] + T[pk >> 16];
            float a = v >= 0.f ? v : ALPHA * v;
            float e = __expf(a);              // no max-shift: logits small
            uint pos = atomicAdd(&cur[row], 1u);
            sDE[pos] = make_uint2(pk >> 16, __float_as_uint(e));
        }
    }
    __syncthreads();

    // (4) per-wave row processing, register accumulation
    const int wv = tid >> 6;
    const int lane = tid & 63;
    const int sub = lane >> 5;
    const int c2 = lane & 31;
    const ushort* hb2 = HB + 2 * c2;

    for (int r = wv; r < SPAN2; r += 8) {
        const int start = (int)off[r];
        const int deg = (int)(off[r + 1] - off[r]);
        float a0 = 0.f, a1 = 0.f, rs = 0.f;
        for (int j = 0; j < deg; j += 16) {
            uint dd[8]; float ee[8];
#pragma unroll
            for (int u = 0; u < 8; ++u) {
                int idx = j + 2 * u + sub;
                int ic = start + (idx < deg ? idx : 0);
                uint2 q = sDE[ic];             // broadcast LDS read
                dd[u] = q.x;
                ee[u] = (idx < deg) ? __uint_as_float(q.y) : 0.f;
            }
            __builtin_amdgcn_sched_barrier(0);  // keep gathers batched
            float f0[8], f1[8];
#pragma unroll
            for (int u = 0; u < 8; ++u) {
                uint g2 = *reinterpret_cast<const uint*>(
                    hb2 + (size_t)dd[u] * DDIM);
                f0[u] = bf2f((ushort)(g2 & 0xffffu));
                f1[u] = bf2f((ushort)(g2 >> 16));
            }
            __builtin_amdgcn_sched_barrier(0);
#pragma unroll
            for (int u = 0; u < 8; ++u) {
                a0 = fmaf(ee[u], f0[u], a0);
                a1 = fmaf(ee[u], f1[u], a1);
                rs += ee[u];
            }
        }
        a0 += __shfl_xor(a0, 32, 64);
        a1 += __shfl_xor(a1, 32, 64);
        rs += __shfl_xor(rs, 32, 64);
        const int node = nb0 + r;
        if (sub == 0 && node < NN) {
            float inv = 1.f / (rs + EPSV);
            reinterpret_cast<float2*>(out + (size_t)node * DDIM)[c2] =
                make_float2(a0 * inv, a1 * inv);
        }
    }
}

extern "C" void kernel_launch(void* const* d_in, const int* in_sizes, int n_in,
                              void* d_out, int out_size, void* d_ws, size_t ws_size,
                              hipStream_t stream) {
    const float* X    = (const float*)d_in[0];
    const int*   edge = (const int*)d_in[1];
    const float* W    = (const float*)d_in[2];
    const float* attn = (const float*)d_in[3];

    uint*   wu = (uint*)d_ws;
    float*  wf = (float*)d_ws;
    float*  S      = wf + O_S;
    float*  T      = wf + O_T;
    ushort* HB     = (ushort*)(wu + O_HB);
    uint4*  WB     = (uint4*)(wu + O_WB);
    uint*   BINCNT = wu + O_BIN;
    uint*   EBUF   = wu + O_EBUF;

    k_prep<<<8, 256, 0, stream>>>(W, BINCNT, WB);
    k_fused<<<FGRID, 256, 0, stream>>>(X, WB, attn, edge, HB, S, T, BINCNT, EBUF);
    k_agg<<<NBIN * 2, 512, 0, stream>>>(EBUF, BINCNT, S, T, HB, (float*)d_out);
}

// Round 7
// 126.359 us; speedup vs baseline: 1.1002x; 1.1002x over previous
//
#include <hip/hip_runtime.h>
#include <stdint.h>

#define NN 50000
#define NE 800000
#define KDIM 256
#define DDIM 64
#define ALPHA 0.2f
#define EPSV 9e-15f

#define NBIN 512
#define BSPAN 98           // nodes per bin; 512*98 = 50176 >= 50000
#define SPAN2 49           // nodes per half-bin (k_agg block granularity)
#define BCAP 2048          // edge capacity per bin (mean 1562, +12 sigma)
#define HCAP 1024          // edge capacity per half-bin
#define PBLK 256           // partition-role blocks (256 -> 6-word EBUF runs)
#define EPB 3125           // edges per partition block (256*3125 = 800000)
#define GEMM_BLOCKS 1024
#define FGRID (PBLK + GEMM_BLOCKS)

// d_ws layout in 4-byte words:
#define O_S    0           // 50000 f32
#define O_T    50000       // 50000 f32
#define O_HB   100000      // 3.2M ushort = 1.6M words (bf16 H)
#define O_WB   1700000     // 2048 uint4 = 8192 words (prepacked bf16 W)
#define O_BIN  1708192     // 512 uint (bin fill counters, zeroed by k_prep)
#define O_EBUF 1708704     // NBIN*BCAP = 1,048,576 words (binned packed edges)
// total 2,757,280 words = 11.03 MB

typedef __bf16 bf16x8 __attribute__((ext_vector_type(8)));
typedef float f32x4 __attribute__((ext_vector_type(4)));

__device__ __forceinline__ ushort f2bf(float f) {
    uint32_t u = __float_as_uint(f);
    return (ushort)((u + 0x7fffu + ((u >> 16) & 1u)) >> 16);  // RNE
}
__device__ __forceinline__ float bf2f(ushort u) {
    return __uint_as_float(((uint32_t)u) << 16);
}
// exact floor(src/98) for src < 89240:  85599*98 - 2^23 = 94
__device__ __forceinline__ uint binof(uint src) {
    return (src * 85599u) >> 23;
}

// ---- K0: prep — pack W to bf16 LDS layout; zero bin counters ----
__global__ __launch_bounds__(256) void k_prep(const float* __restrict__ W,
                                              uint* __restrict__ BINCNT,
                                              uint4* __restrict__ WB) {
    const int g = blockIdx.x * 256 + threadIdx.x;  // 8 blocks -> 2048 threads
    if (g < NBIN) BINCNT[g] = 0u;
    if (g < 2048) {
        int ts = g >> 6;
        int ln = g & 63;
        int s = ts >> 2, t = ts & 3;
        int q = ln >> 4, c = ln & 15;
        union { ushort us[8]; uint4 v; } pk;
#pragma unroll
        for (int j = 0; j < 8; ++j) {
            int k = s * 32 + q * 8 + j;
            pk.us[j] = f2bf(W[k * DDIM + t * 16 + c]);
        }
        WB[g] = pk.v;
    }
}

// ---- K1: fused edge-partition (blocks 0..255) + gemm (blocks 256..1279) ----
__global__ __launch_bounds__(256) void k_fused(const float* __restrict__ X,
                                               const uint4* __restrict__ WB,
                                               const float* __restrict__ attn,
                                               const int* __restrict__ edge,
                                               ushort* __restrict__ HB,
                                               float* __restrict__ S,
                                               float* __restrict__ T,
                                               uint* __restrict__ BINCNT,
                                               uint* __restrict__ EBUF) {
    __shared__ uint4 bsm[2048];  // 32 KB, role-dependent use

    if (blockIdx.x < PBLK) {
        // ---------------- partition role: LDS counting sort by bin ----------
        // layout (words): cnt/cursor 0..511 | binStart 512..1023 |
        //   gbase 1024..1535 | stag 1536..4660 | sorted 4672..7796
        uint* sm = (uint*)bsm;
        const int CNT0 = 0, BST = 512, GBS = 1024, STG = 1536, SRT = 4672;
        const int tid = threadIdx.x;
        const int p0 = blockIdx.x * EPB;
        for (int b = tid; b < NBIN; b += 256) sm[CNT0 + b] = 0u;
        __syncthreads();
        for (int k = tid; k < EPB; k += 256) {
            uint s = (uint)edge[p0 + k];
            uint d = (uint)edge[NE + p0 + k];
            sm[STG + k] = s | (d << 16);
            atomicAdd(&sm[CNT0 + binof(s)], 1u);
        }
        __syncthreads();
        // exclusive scan of cnt -> binStart (wave 0)
        if (tid < 64) {
            uint carry = 0;
            for (int c = 0; c < 8; ++c) {
                uint v = sm[CNT0 + c * 64 + tid];
                uint incl = v;
#pragma unroll
                for (int m = 1; m < 64; m <<= 1) {
                    uint t = __shfl_up(incl, m, 64);
                    if (tid >= m) incl += t;
                }
                sm[BST + c * 64 + tid] = incl - v + carry;
                carry += __shfl(incl, 63, 64);
            }
        }
        __syncthreads();
        // reserve global space per bin; repurpose cnt[] as LDS scatter cursor
        for (int b = tid; b < NBIN; b += 256) {
            uint c = sm[CNT0 + b];
            sm[GBS + b] = c ? atomicAdd(&BINCNT[b], c) : 0u;
            sm[CNT0 + b] = sm[BST + b];
        }
        __syncthreads();
        // LDS scatter: bin-sorted order
        for (int k = tid; k < EPB; k += 256) {
            uint pk = sm[STG + k];
            uint bin = binof(pk & 0xffffu);
            uint slot = atomicAdd(&sm[CNT0 + bin], 1u);
            sm[SRT + slot] = pk;
        }
        __syncthreads();
        // copy-out: bin directly computable from payload (no binary search)
        for (int k = tid; k < EPB; k += 256) {
            uint pk = sm[SRT + k];
            uint bin = binof(pk & 0xffffu);
            uint local = (uint)k - sm[BST + bin] + sm[GBS + bin];
            if (local < BCAP) EBUF[bin * BCAP + local] = pk;
        }
        return;
    }

    // ---------------- gemm role ----------------
    uint4 wreg[8];
#pragma unroll
    for (int j = 0; j < 8; ++j) wreg[j] = WB[j * 256 + threadIdx.x];
#pragma unroll
    for (int j = 0; j < 8; ++j) bsm[j * 256 + threadIdx.x] = wreg[j];
    __syncthreads();

    const int lane = threadIdx.x & 63;
    const int wave = (blockIdx.x - PBLK) * 4 + (threadIdx.x >> 6);
    const int nwaves = GEMM_BLOCKS * 4;  // 4096
    const int quad = lane >> 4;
    const int nn = lane & 15;

    float asrc[4], adst[4];
#pragma unroll
    for (int t = 0; t < 4; ++t) {
        asrc[t] = attn[t * 16 + nn];
        adst[t] = attn[DDIM + t * 16 + nn];
    }

    const int MT = NN / 16;  // 3125
    for (int mt = wave; mt < MT; mt += nwaves) {
        const int row0 = mt * 16;
        const float* xr = X + (size_t)(row0 + nn) * KDIM + quad * 8;
        bf16x8 afrag[8];
#pragma unroll
        for (int s = 0; s < 8; ++s) {
            float4 lo = *reinterpret_cast<const float4*>(xr + s * 32);
            float4 hi = *reinterpret_cast<const float4*>(xr + s * 32 + 4);
            union { uint u[4]; bf16x8 v; } aa;
            asm("v_cvt_pk_bf16_f32 %0, %1, %2"
                : "=v"(aa.u[0]) : "v"(lo.x), "v"(lo.y));
            asm("v_cvt_pk_bf16_f32 %0, %1, %2"
                : "=v"(aa.u[1]) : "v"(lo.z), "v"(lo.w));
            asm("v_cvt_pk_bf16_f32 %0, %1, %2"
                : "=v"(aa.u[2]) : "v"(hi.x), "v"(hi.y));
            asm("v_cvt_pk_bf16_f32 %0, %1, %2"
                : "=v"(aa.u[3]) : "v"(hi.z), "v"(hi.w));
            afrag[s] = aa.v;
        }

        f32x4 acc[4];
#pragma unroll
        for (int t = 0; t < 4; ++t) acc[t] = {0.f, 0.f, 0.f, 0.f};
#pragma unroll
        for (int s = 0; s < 8; ++s)
#pragma unroll
            for (int t = 0; t < 4; ++t) {
                bf16x8 bf = *reinterpret_cast<const bf16x8*>(
                    &bsm[(s * 4 + t) * 64 + lane]);
                acc[t] = __builtin_amdgcn_mfma_f32_16x16x32_bf16(
                    afrag[s], bf, acc[t], 0, 0, 0);
            }

#pragma unroll
        for (int t = 0; t < 4; ++t)
#pragma unroll
            for (int r = 0; r < 4; ++r)
                HB[(size_t)(row0 + quad * 4 + r) * DDIM + t * 16 + nn] =
                    f2bf(acc[t][r]);

        float sp[4], tp[4];
#pragma unroll
        for (int r = 0; r < 4; ++r) { sp[r] = 0.f; tp[r] = 0.f; }
#pragma unroll
        for (int t = 0; t < 4; ++t)
#pragma unroll
            for (int r = 0; r < 4; ++r) {
                sp[r] = fmaf(acc[t][r], asrc[t], sp[r]);
                tp[r] = fmaf(acc[t][r], adst[t], tp[r]);
            }
#pragma unroll
        for (int m = 1; m < 16; m <<= 1)
#pragma unroll
            for (int r = 0; r < 4; ++r) {
                sp[r] += __shfl_xor(sp[r], m, 64);
                tp[r] += __shfl_xor(tp[r], m, 64);
            }
        if (nn == 0) {
#pragma unroll
            for (int r = 0; r < 4; ++r) {
                S[row0 + quad * 4 + r] = sp[r];
                T[row0 + quad * 4 + r] = tp[r];
            }
        }
    }
}

// ---- K2: half-bin aggregation with in-LDS CSR + register accumulation ----
// (byte-identical to round-5 measured-fast version)
__global__ __launch_bounds__(512) void k_agg(const uint* __restrict__ EBUF,
                                             const uint* __restrict__ BINCNT,
                                             const float* __restrict__ S,
                                             const float* __restrict__ T,
                                             const ushort* __restrict__ HB,
                                             float* __restrict__ out) {
    __shared__ uint2 sDE[HCAP];       // (dst, e-bits) row-sorted, 8 KB
    __shared__ uint  cntL[SPAN2];
    __shared__ uint  off[SPAN2 + 1];
    __shared__ uint  cur[SPAN2];
    __shared__ float Sseg[SPAN2];

    const int b = blockIdx.x >> 1;
    const int half = blockIdx.x & 1;
    const int nb0 = b * BSPAN + half * SPAN2;
    const int tid = threadIdx.x;

    if (tid < SPAN2) {
        cntL[tid] = 0u;
        int node = nb0 + tid;
        Sseg[tid] = (node < NN) ? S[node] : 0.f;
    }
    __syncthreads();

    int cnt = (int)BINCNT[b];
    cnt = cnt < BCAP ? cnt : BCAP;
    const uint* eb = EBUF + b * BCAP;

    // (1) histogram of our half's rows
    for (int k = tid; k < cnt; k += 512) {
        int row = (int)(eb[k] & 0xffffu) - nb0;
        if ((unsigned)row < SPAN2) atomicAdd(&cntL[row], 1u);
    }
    __syncthreads();

    // (2) exclusive scan, 49 values, wave 0
    if (tid < 64) {
        uint v = (tid < SPAN2) ? cntL[tid] : 0u;
        uint incl = v;
#pragma unroll
        for (int m = 1; m < 64; m <<= 1) {
            uint t = __shfl_up(incl, m, 64);
            if (tid >= m) incl += t;
        }
        if (tid < SPAN2) { off[tid] = incl - v; cur[tid] = incl - v; }
        if (tid == SPAN2 - 1) off[SPAN2] = incl;
    }
    __syncthreads();

    // (3) scatter + logit computation (edges are L2-hot from pass 1)
    for (int k = tid; k < cnt; k += 512) {
        uint pk = eb[k];
        int row = (int)(pk & 0xffffu) - nb0;
        if ((unsigned)row < SPAN2) {
            float v = Sseg[row] + T[pk >> 16];
            float a = v >= 0.f ? v : ALPHA * v;
            float e = __expf(a);              // no max-shift: logits small
            uint pos = atomicAdd(&cur[row], 1u);
            sDE[pos] = make_uint2(pk >> 16, __float_as_uint(e));
        }
    }
    __syncthreads();

    // (4) per-wave row processing, register accumulation
    const int wv = tid >> 6;
    const int lane = tid & 63;
    const int sub = lane >> 5;
    const int c2 = lane & 31;
    const ushort* hb2 = HB + 2 * c2;

    for (int r = wv; r < SPAN2; r += 8) {
        const int start = (int)off[r];
        const int deg = (int)(off[r + 1] - off[r]);
        float a0 = 0.f, a1 = 0.f, rs = 0.f;
        for (int j = 0; j < deg; j += 16) {
            uint dd[8]; float ee[8];
#pragma unroll
            for (int u = 0; u < 8; ++u) {
                int idx = j + 2 * u + sub;
                int ic = start + (idx < deg ? idx : 0);
                uint2 q = sDE[ic];             // broadcast LDS read
                dd[u] = q.x;
                ee[u] = (idx < deg) ? __uint_as_float(q.y) : 0.f;
            }
            __builtin_amdgcn_sched_barrier(0);  // keep gathers batched
            float f0[8], f1[8];
#pragma unroll
            for (int u = 0; u < 8; ++u) {
                uint g2 = *reinterpret_cast<const uint*>(
                    hb2 + (size_t)dd[u] * DDIM);
                f0[u] = bf2f((ushort)(g2 & 0xffffu));
                f1[u] = bf2f((ushort)(g2 >> 16));
            }
            __builtin_amdgcn_sched_barrier(0);
#pragma unroll
            for (int u = 0; u < 8; ++u) {
                a0 = fmaf(ee[u], f0[u], a0);
                a1 = fmaf(ee[u], f1[u], a1);
                rs += ee[u];
            }
        }
        a0 += __shfl_xor(a0, 32, 64);
        a1 += __shfl_xor(a1, 32, 64);
        rs += __shfl_xor(rs, 32, 64);
        const int node = nb0 + r;
        if (sub == 0 && node < NN) {
            float inv = 1.f / (rs + EPSV);
            reinterpret_cast<float2*>(out + (size_t)node * DDIM)[c2] =
                make_float2(a0 * inv, a1 * inv);
        }
    }
}

extern "C" void kernel_launch(void* const* d_in, const int* in_sizes, int n_in,
                              void* d_out, int out_size, void* d_ws, size_t ws_size,
                              hipStream_t stream) {
    const float* X    = (const float*)d_in[0];
    const int*   edge = (const int*)d_in[1];
    const float* W    = (const float*)d_in[2];
    const float* attn = (const float*)d_in[3];

    uint*   wu = (uint*)d_ws;
    float*  wf = (float*)d_ws;
    float*  S      = wf + O_S;
    float*  T      = wf + O_T;
    ushort* HB     = (ushort*)(wu + O_HB);
    uint4*  WB     = (uint4*)(wu + O_WB);
    uint*   BINCNT = wu + O_BIN;
    uint*   EBUF   = wu + O_EBUF;

    k_prep<<<8, 256, 0, stream>>>(W, BINCNT, WB);
    k_fused<<<FGRID, 256, 0, stream>>>(X, WB, attn, edge, HB, S, T, BINCNT, EBUF);
    k_agg<<<NBIN * 2, 512, 0, stream>>>(EBUF, BINCNT, S, T, HB, (float*)d_out);
}

// Round 8
// 122.362 us; speedup vs baseline: 1.1361x; 1.0327x over previous
//
#include <hip/hip_runtime.h>
#include <stdint.h>

#define NN 50000
#define NE 800000
#define KDIM 256
#define DDIM 64
#define ALPHA 0.2f
#define EPSV 9e-15f

#define NBIN 512
#define BSPAN 98           // nodes per bin; 512*98 = 50176 >= 50000
#define SPAN2 49           // nodes per half-bin (k_agg block granularity)
#define BCAP 2048          // edge capacity per bin (mean 1562, +12 sigma)
#define HCAP 1024          // edge capacity per half-bin
#define PBLK 256           // partition-role blocks (keep 6-word EBUF runs)
#define EPB 3125           // edges per partition block (256*3125 = 800000)
#define GEMM_BLOCKS 512    // x8 waves = 4096 gemm waves
#define FGRID (PBLK + GEMM_BLOCKS)

// d_ws layout in 4-byte words:
#define O_S    0           // 50000 f32
#define O_T    50000       // 50000 f32
#define O_HB   100000      // 3.2M ushort = 1.6M words (bf16 H)
#define O_WB   1700000     // 2048 uint4 = 8192 words (prepacked bf16 W)
#define O_BIN  1708192     // 512 uint (bin fill counters, zeroed by k_prep)
#define O_EBUF 1708704     // NBIN*BCAP = 1,048,576 words (binned packed edges)
// total 2,757,280 words = 11.03 MB

typedef __bf16 bf16x8 __attribute__((ext_vector_type(8)));
typedef float f32x4 __attribute__((ext_vector_type(4)));

__device__ __forceinline__ ushort f2bf(float f) {
    uint32_t u = __float_as_uint(f);
    return (ushort)((u + 0x7fffu + ((u >> 16) & 1u)) >> 16);  // RNE
}
__device__ __forceinline__ float bf2f(ushort u) {
    return __uint_as_float(((uint32_t)u) << 16);
}
// exact floor(src/98) for src < 89240:  85599*98 - 2^23 = 94
__device__ __forceinline__ uint binof(uint src) {
    return (src * 85599u) >> 23;
}

// ---- K0: prep — pack W to bf16 LDS layout; zero bin counters ----
__global__ __launch_bounds__(256) void k_prep(const float* __restrict__ W,
                                              uint* __restrict__ BINCNT,
                                              uint4* __restrict__ WB) {
    const int g = blockIdx.x * 256 + threadIdx.x;  // 8 blocks -> 2048 threads
    if (g < NBIN) BINCNT[g] = 0u;
    if (g < 2048) {
        int ts = g >> 6;
        int ln = g & 63;
        int s = ts >> 2, t = ts & 3;
        int q = ln >> 4, c = ln & 15;
        union { ushort us[8]; uint4 v; } pk;
#pragma unroll
        for (int j = 0; j < 8; ++j) {
            int k = s * 32 + q * 8 + j;
            pk.us[j] = f2bf(W[k * DDIM + t * 16 + c]);
        }
        WB[g] = pk.v;
    }
}

// ---- K1: fused edge-partition (blocks 0..255) + gemm (blocks 256..767) ----
// 512 threads/block: partition tail gets 8 waves/CU (was 4).
__global__ __launch_bounds__(512) void k_fused(const float* __restrict__ X,
                                               const uint4* __restrict__ WB,
                                               const float* __restrict__ attn,
                                               const int* __restrict__ edge,
                                               ushort* __restrict__ HB,
                                               float* __restrict__ S,
                                               float* __restrict__ T,
                                               uint* __restrict__ BINCNT,
                                               uint* __restrict__ EBUF) {
    __shared__ uint4 bsm[2048];  // 32 KB, role-dependent use

    if (blockIdx.x < PBLK) {
        // ---------------- partition role: LDS counting sort by bin ----------
        // layout (words): cnt/cursor 0..511 | binStart 512..1023 |
        //   gbase 1024..1535 | stag 1536..4660 | sorted 4672..7796
        uint* sm = (uint*)bsm;
        const int CNT0 = 0, BST = 512, GBS = 1024, STG = 1536, SRT = 4672;
        const int tid = threadIdx.x;
        const int p0 = blockIdx.x * EPB;
        for (int b = tid; b < NBIN; b += 512) sm[CNT0 + b] = 0u;
        __syncthreads();
        for (int k = tid; k < EPB; k += 512) {
            uint s = (uint)edge[p0 + k];
            uint d = (uint)edge[NE + p0 + k];
            sm[STG + k] = s | (d << 16);
            atomicAdd(&sm[CNT0 + binof(s)], 1u);
        }
        __syncthreads();
        // exclusive scan of cnt -> binStart (wave 0)
        if (tid < 64) {
            uint carry = 0;
            for (int c = 0; c < 8; ++c) {
                uint v = sm[CNT0 + c * 64 + tid];
                uint incl = v;
#pragma unroll
                for (int m = 1; m < 64; m <<= 1) {
                    uint t = __shfl_up(incl, m, 64);
                    if (tid >= m) incl += t;
                }
                sm[BST + c * 64 + tid] = incl - v + carry;
                carry += __shfl(incl, 63, 64);
            }
        }
        __syncthreads();
        // reserve global space per bin; repurpose cnt[] as LDS scatter cursor
        for (int b = tid; b < NBIN; b += 512) {
            uint c = sm[CNT0 + b];
            sm[GBS + b] = c ? atomicAdd(&BINCNT[b], c) : 0u;
            sm[CNT0 + b] = sm[BST + b];
        }
        __syncthreads();
        // LDS scatter: bin-sorted order
        for (int k = tid; k < EPB; k += 512) {
            uint pk = sm[STG + k];
            uint bin = binof(pk & 0xffffu);
            uint slot = atomicAdd(&sm[CNT0 + bin], 1u);
            sm[SRT + slot] = pk;
        }
        __syncthreads();
        // copy-out: bin directly computable from payload (no binary search)
        for (int k = tid; k < EPB; k += 512) {
            uint pk = sm[SRT + k];
            uint bin = binof(pk & 0xffffu);
            uint local = (uint)k - sm[BST + bin] + sm[GBS + bin];
            if (local < BCAP) EBUF[bin * BCAP + local] = pk;
        }
        return;
    }

    // ---------------- gemm role (8 waves/block) ----------------
    uint4 wreg[4];
#pragma unroll
    for (int j = 0; j < 4; ++j) wreg[j] = WB[j * 512 + threadIdx.x];
#pragma unroll
    for (int j = 0; j < 4; ++j) bsm[j * 512 + threadIdx.x] = wreg[j];
    __syncthreads();

    const int lane = threadIdx.x & 63;
    const int wave = (blockIdx.x - PBLK) * 8 + (threadIdx.x >> 6);
    const int nwaves = GEMM_BLOCKS * 8;  // 4096
    const int quad = lane >> 4;
    const int nn = lane & 15;

    float asrc[4], adst[4];
#pragma unroll
    for (int t = 0; t < 4; ++t) {
        asrc[t] = attn[t * 16 + nn];
        adst[t] = attn[DDIM + t * 16 + nn];
    }

    const int MT = NN / 16;  // 3125
    for (int mt = wave; mt < MT; mt += nwaves) {
        const int row0 = mt * 16;
        const float* xr = X + (size_t)(row0 + nn) * KDIM + quad * 8;
        bf16x8 afrag[8];
#pragma unroll
        for (int s = 0; s < 8; ++s) {
            float4 lo = *reinterpret_cast<const float4*>(xr + s * 32);
            float4 hi = *reinterpret_cast<const float4*>(xr + s * 32 + 4);
            union { uint u[4]; bf16x8 v; } aa;
            asm("v_cvt_pk_bf16_f32 %0, %1, %2"
                : "=v"(aa.u[0]) : "v"(lo.x), "v"(lo.y));
            asm("v_cvt_pk_bf16_f32 %0, %1, %2"
                : "=v"(aa.u[1]) : "v"(lo.z), "v"(lo.w));
            asm("v_cvt_pk_bf16_f32 %0, %1, %2"
                : "=v"(aa.u[2]) : "v"(hi.x), "v"(hi.y));
            asm("v_cvt_pk_bf16_f32 %0, %1, %2"
                : "=v"(aa.u[3]) : "v"(hi.z), "v"(hi.w));
            afrag[s] = aa.v;
        }

        f32x4 acc[4];
#pragma unroll
        for (int t = 0; t < 4; ++t) acc[t] = {0.f, 0.f, 0.f, 0.f};
#pragma unroll
        for (int s = 0; s < 8; ++s)
#pragma unroll
            for (int t = 0; t < 4; ++t) {
                bf16x8 bf = *reinterpret_cast<const bf16x8*>(
                    &bsm[(s * 4 + t) * 64 + lane]);
                acc[t] = __builtin_amdgcn_mfma_f32_16x16x32_bf16(
                    afrag[s], bf, acc[t], 0, 0, 0);
            }

#pragma unroll
        for (int t = 0; t < 4; ++t)
#pragma unroll
            for (int r = 0; r < 4; ++r)
                HB[(size_t)(row0 + quad * 4 + r) * DDIM + t * 16 + nn] =
                    f2bf(acc[t][r]);

        float sp[4], tp[4];
#pragma unroll
        for (int r = 0; r < 4; ++r) { sp[r] = 0.f; tp[r] = 0.f; }
#pragma unroll
        for (int t = 0; t < 4; ++t)
#pragma unroll
            for (int r = 0; r < 4; ++r) {
                sp[r] = fmaf(acc[t][r], asrc[t], sp[r]);
                tp[r] = fmaf(acc[t][r], adst[t], tp[r]);
            }
#pragma unroll
        for (int m = 1; m < 16; m <<= 1)
#pragma unroll
            for (int r = 0; r < 4; ++r) {
                sp[r] += __shfl_xor(sp[r], m, 64);
                tp[r] += __shfl_xor(tp[r], m, 64);
            }
        if (nn == 0) {
#pragma unroll
            for (int r = 0; r < 4; ++r) {
                S[row0 + quad * 4 + r] = sp[r];
                T[row0 + quad * 4 + r] = tp[r];
            }
        }
    }
}

// ---- K2: half-bin aggregation; quarter-wave uint2 gathers ----
// Per edge: 16 lanes x uint2 (8 B) cover the 128-B HB row. Per 16-edge
// batch: 4 gather instrs (was 8), 4 accumulators/lane, xor16+xor32 combine.
__global__ __launch_bounds__(512) void k_agg(const uint* __restrict__ EBUF,
                                             const uint* __restrict__ BINCNT,
                                             const float* __restrict__ S,
                                             const float* __restrict__ T,
                                             const ushort* __restrict__ HB,
                                             float* __restrict__ out) {
    __shared__ uint2 sDE[HCAP];       // (dst, e-bits) row-sorted, 8 KB
    __shared__ uint  cntL[SPAN2];
    __shared__ uint  off[SPAN2 + 1];
    __shared__ uint  cur[SPAN2];
    __shared__ float Sseg[SPAN2];

    const int b = blockIdx.x >> 1;
    const int half = blockIdx.x & 1;
    const int nb0 = b * BSPAN + half * SPAN2;
    const int tid = threadIdx.x;

    if (tid < SPAN2) {
        cntL[tid] = 0u;
        int node = nb0 + tid;
        Sseg[tid] = (node < NN) ? S[node] : 0.f;
    }
    __syncthreads();

    int cnt = (int)BINCNT[b];
    cnt = cnt < BCAP ? cnt : BCAP;
    const uint* eb = EBUF + b * BCAP;

    // (1) histogram of our half's rows
    for (int k = tid; k < cnt; k += 512) {
        int row = (int)(eb[k] & 0xffffu) - nb0;
        if ((unsigned)row < SPAN2) atomicAdd(&cntL[row], 1u);
    }
    __syncthreads();

    // (2) exclusive scan, 49 values, wave 0
    if (tid < 64) {
        uint v = (tid < SPAN2) ? cntL[tid] : 0u;
        uint incl = v;
#pragma unroll
        for (int m = 1; m < 64; m <<= 1) {
            uint t = __shfl_up(incl, m, 64);
            if (tid >= m) incl += t;
        }
        if (tid < SPAN2) { off[tid] = incl - v; cur[tid] = incl - v; }
        if (tid == SPAN2 - 1) off[SPAN2] = incl;
    }
    __syncthreads();

    // (3) scatter + logit computation (edges are L2-hot from pass 1)
    for (int k = tid; k < cnt; k += 512) {
        uint pk = eb[k];
        int row = (int)(pk & 0xffffu) - nb0;
        if ((unsigned)row < SPAN2) {
            float v = Sseg[row] + T[pk >> 16];
            float a = v >= 0.f ? v : ALPHA * v;
            float e = __expf(a);              // no max-shift: logits small
            uint pos = atomicAdd(&cur[row], 1u);
            sDE[pos] = make_uint2(pk >> 16, __float_as_uint(e));
        }
    }
    __syncthreads();

    // (4) per-wave row processing, quarter-wave edges, register accumulation
    const int wv = tid >> 6;
    const int lane = tid & 63;
    const int sub4 = lane >> 4;   // which quarter-wave (edge slot)
    const int c4 = lane & 15;     // column quad index: cols 4*c4..4*c4+3
    const ushort* hb4 = HB + 4 * c4;

    for (int r = wv; r < SPAN2; r += 8) {
        const int start = (int)off[r];
        const int deg = (int)(off[r + 1] - off[r]);
        float a0 = 0.f, a1 = 0.f, a2 = 0.f, a3 = 0.f, rs = 0.f;
        for (int j = 0; j < deg; j += 16) {
            uint dd[4]; float ee[4];
#pragma unroll
            for (int u = 0; u < 4; ++u) {
                int idx = j + 4 * u + sub4;
                int ic = start + (idx < deg ? idx : 0);
                uint2 q = sDE[ic];             // broadcast LDS read
                dd[u] = q.x;
                ee[u] = (idx < deg) ? __uint_as_float(q.y) : 0.f;
            }
            __builtin_amdgcn_sched_barrier(0);  // keep gathers batched
            uint2 g[4];
#pragma unroll
            for (int u = 0; u < 4; ++u)
                g[u] = *reinterpret_cast<const uint2*>(
                    hb4 + (size_t)dd[u] * DDIM);
            __builtin_amdgcn_sched_barrier(0);
#pragma unroll
            for (int u = 0; u < 4; ++u) {
                a0 = fmaf(ee[u], bf2f((ushort)(g[u].x & 0xffffu)), a0);
                a1 = fmaf(ee[u], bf2f((ushort)(g[u].x >> 16)), a1);
                a2 = fmaf(ee[u], bf2f((ushort)(g[u].y & 0xffffu)), a2);
                a3 = fmaf(ee[u], bf2f((ushort)(g[u].y >> 16)), a3);
                rs += ee[u];
            }
        }
        // combine the 4 quarter-waves
#pragma unroll
        for (int m = 16; m < 64; m <<= 1) {
            a0 += __shfl_xor(a0, m, 64);
            a1 += __shfl_xor(a1, m, 64);
            a2 += __shfl_xor(a2, m, 64);
            a3 += __shfl_xor(a3, m, 64);
            rs += __shfl_xor(rs, m, 64);
        }
        const int node = nb0 + r;
        if (sub4 == 0 && node < NN) {
            float inv = 1.f / (rs + EPSV);
            float4 o = make_float4(a0 * inv, a1 * inv, a2 * inv, a3 * inv);
            *reinterpret_cast<float4*>(out + (size_t)node * DDIM + 4 * c4) = o;
        }
    }
}

extern "C" void kernel_launch(void* const* d_in, const int* in_sizes, int n_in,
                              void* d_out, int out_size, void* d_ws, size_t ws_size,
                              hipStream_t stream) {
    const float* X    = (const float*)d_in[0];
    const int*   edge = (const int*)d_in[1];
    const float* W    = (const float*)d_in[2];
    const float* attn = (const float*)d_in[3];

    uint*   wu = (uint*)d_ws;
    float*  wf = (float*)d_ws;
    float*  S      = wf + O_S;
    float*  T      = wf + O_T;
    ushort* HB     = (ushort*)(wu + O_HB);
    uint4*  WB     = (uint4*)(wu + O_WB);
    uint*   BINCNT = wu + O_BIN;
    uint*   EBUF   = wu + O_EBUF;

    k_prep<<<8, 256, 0, stream>>>(W, BINCNT, WB);
    k_fused<<<FGRID, 512, 0, stream>>>(X, WB, attn, edge, HB, S, T, BINCNT, EBUF);
    k_agg<<<NBIN * 2, 512, 0, stream>>>(EBUF, BINCNT, S, T, HB, (float*)d_out);
}